// Round 1
// baseline (220.854 us; speedup 1.0000x reference)
//
#include <hip/hip_runtime.h>
#include <hip/hip_bf16.h>

#define B_ 4
#define N_ 256
#define D_ 256
#define KG_ 128
#define EPS_ 1e-5f

typedef __bf16 bf16x8 __attribute__((ext_vector_type(8)));
typedef float  f32x4v __attribute__((ext_vector_type(4)));

// ---------------------------------------------------------------------------
// S1: W_kcT[d][g] = sum_k W_kg[g][k] * Wc[k][d]   (bf16, transposed for MFMA B)
//     bias_tot[d] = sum_k b_kg[k] * Wc[k][d] + b1l[d]
// Wc = W1l rows [2D, 3D)
// grid: KG_+1 blocks x 256 threads (block KG_ does the bias)
// ---------------------------------------------------------------------------
__global__ __launch_bounds__(256) void s1_kernel(
    const float* __restrict__ Wkg, const float* __restrict__ W1l,
    const float* __restrict__ bkg, const float* __restrict__ b1l,
    __bf16* __restrict__ WkcT, float* __restrict__ biastot)
{
    const int d = threadIdx.x;
    if (blockIdx.x == KG_) {
        float acc = 0.f;
        for (int k = 0; k < D_; ++k)
            acc += bkg[k] * W1l[(2 * D_ + k) * D_ + d];
        biastot[d] = acc + b1l[d];
        return;
    }
    const int g = blockIdx.x;
    float acc = 0.f;
    for (int k = 0; k < D_; ++k)
        acc += Wkg[g * D_ + k] * W1l[(2 * D_ + k) * D_ + d];
    WkcT[d * KG_ + g] = (__bf16)acc;
}

// ---------------------------------------------------------------------------
// S2: a_pb[row][d] = (h @ Wa)[row][d] + bias_tot[d]
//     bb  [row][d] = (h @ Wb)[row][d]
// Wa = W1l rows [0,D), Wb = W1l rows [D,2D). 4 rows per block, fp32 exact.
// ---------------------------------------------------------------------------
__global__ __launch_bounds__(256) void s2_kernel(
    const float* __restrict__ hin, const float* __restrict__ W1l,
    const float* __restrict__ biastot,
    float* __restrict__ apb, float* __restrict__ bbout)
{
    __shared__ float hT[D_][4]; // transposed h tile: hT[e][r]
    const int tid = threadIdx.x;
    const int R = blockIdx.x * 4;
    {
        const int r = tid & 3, c4 = (tid >> 2) << 2;
        const float4 v = *(const float4*)(hin + (R + r) * D_ + c4);
        hT[c4 + 0][r] = v.x; hT[c4 + 1][r] = v.y;
        hT[c4 + 2][r] = v.z; hT[c4 + 3][r] = v.w;
    }
    __syncthreads();
    float aa[4] = {0.f, 0.f, 0.f, 0.f};
    float ab[4] = {0.f, 0.f, 0.f, 0.f};
#pragma unroll 4
    for (int e = 0; e < D_; ++e) {
        const float wa = W1l[e * D_ + tid];
        const float wb = W1l[(D_ + e) * D_ + tid];
        const float4 hv = *(const float4*)&hT[e][0];
        aa[0] += hv.x * wa; aa[1] += hv.y * wa; aa[2] += hv.z * wa; aa[3] += hv.w * wa;
        ab[0] += hv.x * wb; ab[1] += hv.y * wb; ab[2] += hv.z * wb; ab[3] += hv.w * wb;
    }
    const float bt = biastot[tid];
#pragma unroll
    for (int r = 0; r < 4; ++r) {
        apb[(R + r) * D_ + tid]   = aa[r] + bt;
        bbout[(R + r) * D_ + tid] = ab[r];
    }
}

// ---------------------------------------------------------------------------
// BIG: one block per (b,i). 4 waves, wave w owns d in [64w, 64w+64).
//  main loop over j-tiles (16 j):  c = E_tile(16x128,bf16) @ W_kc(128x256,bf16)
//  epilogue: r[d] += adj[b,i,j] * relu(c + a_pb[i,d] + bb[j,d])
//  tail: msg[d] = r @ W2 + deg*b2 ; h_out = LN(h_in + msg)*gamma + beta
// ---------------------------------------------------------------------------
__global__ __launch_bounds__(256, 3) void big_kernel(
    const float* __restrict__ rel, const int* __restrict__ adj,
    const __bf16* __restrict__ WkcT, const float* __restrict__ apb,
    const float* __restrict__ bb, const float* __restrict__ W2l,
    const float* __restrict__ b2l, const float* __restrict__ hin,
    const float* __restrict__ gmm, const float* __restrict__ bta,
    float* __restrict__ hout)
{
    __shared__ __align__(16) __bf16 Et[2][16 * KG_];   // swizzled E tiles
    __shared__ float bbL[2][16][D_ + 4];               // padded bb tiles
    __shared__ float adjL[N_];
    __shared__ float rL[D_];
    __shared__ float red[8];
    __shared__ float sdeg;

    const int tid = threadIdx.x;
    const int lane = tid & 63;
    const int w = tid >> 6;
    const int l15 = lane & 15;
    const int lg = lane >> 4;     // 0..3
    const int bi = blockIdx.x;    // b*256 + i
    const int dw = w * 64;

    const float* Ebase  = rel + (size_t)bi * N_ * KG_;
    const float* bbBase = bb + (size_t)(bi >> 8) * N_ * D_;

    // persistent W fragments in registers: wf[nb][kk] covers
    // d = dw + nb*16 + (lane&15), k = kk*32 + (lane>>4)*8 .. +8
    bf16x8 wf[4][4];
#pragma unroll
    for (int nb = 0; nb < 4; ++nb)
#pragma unroll
        for (int kk = 0; kk < 4; ++kk)
            wf[nb][kk] = *(const bf16x8*)(WkcT + (dw + nb * 16 + l15) * KG_ + kk * 32 + lg * 8);

    float apbv[4];
#pragma unroll
    for (int nb = 0; nb < 4; ++nb)
        apbv[nb] = apb[bi * D_ + dw + nb * 16 + l15];

    adjL[tid] = (float)adj[bi * N_ + tid];

    float racc[4] = {0.f, 0.f, 0.f, 0.f};

    auto stage = [&](int jb, int buf) {
        // E tile: 16 j x 128 k f32 -> bf16, XOR-swizzled rows
        const int jp = tid >> 4;          // 0..15
        const int k0 = (tid & 15) * 8;    // 0..120
        const float* src = Ebase + (jb * 16 + jp) * KG_ + k0;
        const float4 f0 = *(const float4*)src;
        const float4 f1 = *(const float4*)(src + 4);
        bf16x8 v;
        v[0] = (__bf16)f0.x; v[1] = (__bf16)f0.y; v[2] = (__bf16)f0.z; v[3] = (__bf16)f0.w;
        v[4] = (__bf16)f1.x; v[5] = (__bf16)f1.y; v[6] = (__bf16)f1.z; v[7] = (__bf16)f1.w;
        int off = jp * 256 + k0 * 2;
        off ^= (jp & 7) << 4;
        *(bf16x8*)((char*)&Et[buf][0] + off) = v;
        // bb tile: 16 j x 256 d f32
#pragma unroll
        for (int c = 0; c < 4; ++c) {
            const int flat = tid + c * 256;     // float4 index
            const int row = flat >> 6;          // 0..15
            const int c4 = (flat & 63) * 4;
            *(float4*)&bbL[buf][row][c4] = *(const float4*)(bbBase + (jb * 16 + row) * D_ + c4);
        }
    };

    stage(0, 0);
    __syncthreads();

#pragma unroll 2
    for (int jb = 0; jb < 16; ++jb) {
        const int buf = jb & 1;
        if (jb + 1 < 16) stage(jb + 1, buf ^ 1);

        bf16x8 af[4];
#pragma unroll
        for (int kk = 0; kk < 4; ++kk) {
            int off = l15 * 256 + kk * 64 + lg * 16;
            off ^= (l15 & 7) << 4;
            af[kk] = *(const bf16x8*)((const char*)&Et[buf][0] + off);
        }
#pragma unroll
        for (int nb = 0; nb < 4; ++nb) {
            f32x4v acc = {0.f, 0.f, 0.f, 0.f};
#pragma unroll
            for (int kk = 0; kk < 4; ++kk)
                acc = __builtin_amdgcn_mfma_f32_16x16x32_bf16(af[kk], wf[nb][kk], acc, 0, 0, 0);
#pragma unroll
            for (int q = 0; q < 4; ++q) {
                const int jl = lg * 4 + q;  // C layout: row=(lane>>4)*4+q, col=lane&15
                float t = acc[q] + apbv[nb] + bbL[buf][jl][dw + nb * 16 + l15];
                t = fmaxf(t, 0.f);
                racc[nb] += t * adjL[jb * 16 + jl];
            }
        }
        __syncthreads();
    }

    // reduce r over the 4 lane-groups (different j subsets), same d
#pragma unroll
    for (int nb = 0; nb < 4; ++nb) {
        float v = racc[nb];
        v += __shfl_xor(v, 16, 64);
        v += __shfl_xor(v, 32, 64);
        if (lg == 0) rL[dw + nb * 16 + l15] = v;
    }
    // deg = sum_j adj
    if (w == 0) {
        float s = adjL[lane] + adjL[lane + 64] + adjL[lane + 128] + adjL[lane + 192];
#pragma unroll
        for (int off = 32; off >= 1; off >>= 1) s += __shfl_xor(s, off, 64);
        if (lane == 0) sdeg = s;
    }
    __syncthreads();

    // msg = r @ W2 (fp32), residual, LayerNorm
    const int d = tid;
    float m0 = 0.f, m1 = 0.f, m2 = 0.f, m3 = 0.f;
    for (int e = 0; e < D_; e += 4) {
        const float4 rv = *(const float4*)&rL[e];
        m0 += rv.x * W2l[(e + 0) * D_ + d];
        m1 += rv.y * W2l[(e + 1) * D_ + d];
        m2 += rv.z * W2l[(e + 2) * D_ + d];
        m3 += rv.w * W2l[(e + 3) * D_ + d];
    }
    const float t = hin[bi * D_ + d] + (m0 + m1) + (m2 + m3) + sdeg * b2l[d];

    float s = t, sq = t * t;
#pragma unroll
    for (int off = 32; off >= 1; off >>= 1) {
        s  += __shfl_xor(s, off, 64);
        sq += __shfl_xor(sq, off, 64);
    }
    if (lane == 0) { red[w] = s; red[4 + w] = sq; }
    __syncthreads();
    const float S  = red[0] + red[1] + red[2] + red[3];
    const float SQ = red[4] + red[5] + red[6] + red[7];
    const float mu = S * (1.f / D_);
    const float var = SQ * (1.f / D_) - mu * mu;
    const float rstd = rsqrtf(var + EPS_);
    hout[bi * D_ + d] = (t - mu) * rstd * gmm[d] + bta[d];
}

// ---------------------------------------------------------------------------
extern "C" void kernel_launch(void* const* d_in, const int* in_sizes, int n_in,
                              void* d_out, int out_size, void* d_ws, size_t ws_size,
                              hipStream_t stream)
{
    const float* node  = (const float*)d_in[0];
    const float* rel   = (const float*)d_in[1];
    const int*   adj   = (const int*)d_in[2];
    const float* Wkg   = (const float*)d_in[3];
    const float* bkg   = (const float*)d_in[4];
    const float* W1    = (const float*)d_in[5];
    const float* b1    = (const float*)d_in[6];
    const float* W2    = (const float*)d_in[7];
    const float* b2    = (const float*)d_in[8];
    const float* gamma = (const float*)d_in[9];
    const float* beta  = (const float*)d_in[10];
    float* out = (float*)d_out;

    char* ws = (char*)d_ws;
    float*  h1    = (float*)(ws);                       // 1 MB
    float*  apb   = (float*)(ws + (1 << 20));           // 1 MB
    float*  bbuf  = (float*)(ws + (2 << 20));           // 1 MB
    float*  bias  = (float*)(ws + (3 << 20));           // 1 KB
    __bf16* WkcT  = (__bf16*)(ws + (3 << 20) + 4096);   // 64 KB

    for (int l = 0; l < 2; ++l) {
        const float* W1l = W1 + (size_t)l * 3 * D_ * D_;
        const float* hin = (l == 0) ? node : h1;
        float* hout = (l == 1) ? out : h1;

        s1_kernel<<<KG_ + 1, 256, 0, stream>>>(Wkg, W1l, bkg, b1 + l * D_, WkcT, bias);
        s2_kernel<<<(B_ * N_) / 4, 256, 0, stream>>>(hin, W1l, bias, apb, bbuf);
        big_kernel<<<B_ * N_, 256, 0, stream>>>(rel, adj, WkcT, apb, bbuf,
                                                W2 + (size_t)l * D_ * D_, b2 + l * D_,
                                                hin, gamma, beta, hout);
    }
}